// Round 6
// baseline (279.290 us; speedup 1.0000x reference)
//
#include <hip/hip_runtime.h>

#define D 128
#define BROWS 512       // rows per coarse bucket
#define LOGB 9
#define NBMAX 256       // max buckets (N <= 131072)
#define CAP 9216        // entries per bucket region (mean 8192, +11 sigma)
#define CHUNK 4096      // edges per k_bin chunk

typedef __attribute__((ext_vector_type(8))) short bf16x8;
typedef __attribute__((ext_vector_type(4))) float f32x4;

__device__ inline unsigned short f2bf(float f) {
    unsigned u = __float_as_uint(f);
    u += 0x7FFFu + ((u >> 16) & 1u);
    return (unsigned short)(u >> 16);
}
__device__ inline float bf2f(unsigned short h) {
    return __uint_as_float((unsigned)h << 16);
}
__device__ inline float bflo(unsigned u) { return __uint_as_float(u << 16); }
__device__ inline float bfhi(unsigned u) { return __uint_as_float(u & 0xFFFF0000u); }

// Bin edges into NB coarse buckets; packed entry = (local_row<<17)|col.
// Blocks 0-7 additionally pre-convert W to bf16 hi/lo (once for the pipeline).
__global__ __launch_bounds__(512) void k_bin(const int* __restrict__ row,
                                             const int* __restrict__ col,
                                             int E, int* __restrict__ gcur,
                                             unsigned* __restrict__ ebuf,
                                             const float* __restrict__ W,
                                             unsigned short* __restrict__ Wbh,
                                             unsigned short* __restrict__ Wbl) {
    __shared__ int lhist[NBMAX];
    __shared__ int sc[NBMAX];
    __shared__ int gbase[NBMAX];
    __shared__ unsigned sstage[CHUNK];
    __shared__ int sdest[CHUNK];
    int t = threadIdx.x;
    if (blockIdx.x < 8) {   // W -> bf16 hi/lo, 2048 elements per block
        int base = blockIdx.x * 2048 + t;
        #pragma unroll
        for (int i = 0; i < 4; ++i) {
            int idx = base + i * 512;
            float wv = W[idx];
            unsigned short h = f2bf(wv);
            Wbh[idx] = h;
            Wbl[idx] = f2bf(wv - bf2f(h));
        }
    }
    int base = blockIdx.x * CHUNK;
    if (t < NBMAX) lhist[t] = 0;
    __syncthreads();
    int b[8], p[8]; unsigned pk[8];
    #pragma unroll
    for (int i = 0; i < 8; ++i) {
        int idx = base + i * 512 + t;
        if (idx < E) {
            int r = row[idx], c = col[idx];
            b[i] = r >> LOGB;
            pk[i] = ((unsigned)(r & (BROWS - 1)) << 17) | (unsigned)c;
            p[i] = atomicAdd(&lhist[b[i]], 1);
        } else b[i] = -1;
    }
    __syncthreads();
    if (t < 64) {   // wave-0 scan, 4 bins per lane (256 bins)
        int a0 = lhist[4*t], a1 = lhist[4*t+1], a2 = lhist[4*t+2], a3 = lhist[4*t+3];
        int s = a0 + a1 + a2 + a3;
        int incl = s;
        #pragma unroll
        for (int m = 1; m < 64; m <<= 1) {
            int tmp = __shfl_up(incl, m);
            if (t >= m) incl += tmp;
        }
        int excl = incl - s;
        sc[4*t] = excl; sc[4*t+1] = excl + a0;
        sc[4*t+2] = excl + a0 + a1; sc[4*t+3] = excl + a0 + a1 + a2;
        if (a0 > 0) gbase[4*t]   = atomicAdd(&gcur[4*t],   a0);
        if (a1 > 0) gbase[4*t+1] = atomicAdd(&gcur[4*t+1], a1);
        if (a2 > 0) gbase[4*t+2] = atomicAdd(&gcur[4*t+2], a2);
        if (a3 > 0) gbase[4*t+3] = atomicAdd(&gcur[4*t+3], a3);
    }
    __syncthreads();
    #pragma unroll
    for (int i = 0; i < 8; ++i) {
        if (b[i] >= 0) {
            int lidx = sc[b[i]] + p[i];
            int rel = gbase[b[i]] + p[i];
            sstage[lidx] = pk[i];
            sdest[lidx] = (rel < CAP) ? (b[i] * CAP + rel) : -1;
        }
    }
    __syncthreads();
    int total = sc[NBMAX - 1] + lhist[NBMAX - 1];
    for (int i = t; i < total; i += 512) {
        int d = sdest[i];
        if (d >= 0) ebuf[d] = sstage[i];
    }
}

// One block per bucket: stage bucket in LDS, degree hist + scan -> dvals/rptr,
// counting-sort csr_col, then cast this bucket's x rows to pre-scaled bf16
// (merged k_cast — dvals already in LDS).
__global__ __launch_bounds__(1024) void k_group(const int* __restrict__ gcur,
                                                const unsigned* __restrict__ ebuf,
                                                const float* __restrict__ x,
                                                int N, int NBK,
                                                float* __restrict__ dvals,
                                                int* __restrict__ rptr,
                                                int* __restrict__ csr_col,
                                                unsigned short* __restrict__ xs) {
    __shared__ unsigned sebuf[CAP];   // 36 KB
    __shared__ int lhist[BROWS];      // hist, then cursor
    __shared__ float sdl[BROWS];      // per-row d for the cast phase
    __shared__ int wtot[8];
    __shared__ int woff[8];
    __shared__ int sebase;
    int bkt = blockIdx.x, t = threadIdx.x;
    int cnt = gcur[bkt]; if (cnt > CAP) cnt = CAP;
    if (t < 64) {
        int acc = 0;
        for (int i = t; i < bkt; i += 64) {
            int g = gcur[i];
            acc += (g > CAP) ? CAP : g;
        }
        #pragma unroll
        for (int m = 1; m < 64; m <<= 1) acc += __shfl_xor(acc, m);
        if (t == 0) sebase = acc;
    }
    if (t < BROWS) lhist[t] = 0;
    __syncthreads();
    const unsigned* ep = ebuf + (size_t)bkt * CAP;
    for (int i = t; i < cnt; i += 1024) {
        unsigned e = ep[i];
        sebuf[i] = e;
        atomicAdd(&lhist[e >> 17], 1);
    }
    __syncthreads();
    int lane = t & 63, wv = t >> 6;
    int v = 0, incl = 0;
    if (t < BROWS) {    // 8 waves scan 512 degrees
        v = lhist[t];
        incl = v;
        #pragma unroll
        for (int m = 1; m < 64; m <<= 1) {
            int tmp = __shfl_up(incl, m);
            if (lane >= m) incl += tmp;
        }
        if (lane == 63) wtot[wv] = incl;
    }
    __syncthreads();
    if (t < 8) {
        int w = wtot[t];
        int wincl = w;
        #pragma unroll
        for (int m = 1; m < 8; m <<= 1) {
            int tmp = __shfl_up(wincl, m);
            if (t >= m) wincl += tmp;
        }
        woff[t] = wincl - w;
    }
    __syncthreads();
    int ebase = sebase;
    if (t < BROWS) {
        int excl = woff[wv] + incl - v;
        int r = (bkt << LOGB) + t;
        float dl = rsqrtf((float)v);
        if (r < N) {
            rptr[r] = ebase + excl;
            dvals[r] = dl;
        }
        sdl[t] = dl;
        lhist[t] = excl;              // becomes running cursor
    }
    if (bkt == NBK - 1 && t == 0) rptr[N] = ebase + cnt;
    if (bkt == 0 && t == 0) dvals[N] = 0.f;   // pad target for unconditional sd
    __syncthreads();
    for (int i = t; i < cnt; i += 1024) {
        unsigned e = sebuf[i];
        int rr = (int)(e >> 17);
        int p = atomicAdd(&lhist[rr], 1);
        csr_col[ebase + p] = (int)(e & 0x1FFFFu);
    }
    // cast phase: xs[r][:] = bf16(d[r] * x[r][:]) for this bucket's rows
    int rb = bkt << LOGB;
    const float4* x4 = (const float4*)x;
    for (int idx = t; idx < BROWS * 32; idx += 1024) {
        int rl = idx >> 5;
        int r = rb + rl;
        if (r < N) {
            float4 vv = x4[(size_t)r * 32 + (idx & 31)];
            float d = sdl[rl];
            ushort4 o = make_ushort4(f2bf(d * vv.x), f2bf(d * vv.y),
                                     f2bf(d * vv.z), f2bf(d * vv.w));
            ((ushort4*)xs)[(size_t)r * 32 + (idx & 31)] = o;
        }
    }
    if (bkt == 0 && t < 64)   // zero row N (gather pad target)
        ((unsigned*)(xs + (size_t)N * D))[t] = 0u;
}

#define ACC8(A, v) do { \
    A[0] += bflo((v).x); A[1] += bfhi((v).x); \
    A[2] += bflo((v).y); A[3] += bfhi((v).y); \
    A[4] += bflo((v).z); A[5] += bfhi((v).z); \
    A[6] += bflo((v).w); A[7] += bfhi((v).w); } while (0)

// Wave per TWO rows, interleaved. Each row uses 16-wide edge chunks (pad-16:
// ~1.44x ACC work vs round-5's pad-32 ~2x) with 4 unconditional zero-padded
// loads per row per chunk; both rows' batches issued back-to-back -> 8 loads
// (2 KB) in flight, pinned by one sched_barrier between loads and ACCs.
// Round-5 lesson: depth must not come from wider per-row padding (VALU waste);
// it comes from independent rows.
__global__ __launch_bounds__(256) void k_rows(const unsigned short* __restrict__ xs,
                                              const int* __restrict__ rptr,
                                              const int* __restrict__ csr_col,
                                              const float* __restrict__ dvals,
                                              float* __restrict__ ssum,
                                              float* __restrict__ y, int N) {
    int wv = (blockIdx.x * blockDim.x + threadIdx.x) >> 6;
    int r0 = wv * 2;
    if (r0 >= N) return;
    int r1 = r0 + 1;
    bool has1 = (r1 < N);
    int lane = threadIdx.x & 63;
    int grp = lane >> 4, sl = lane & 15;
    const uint4* xsv = (const uint4*)xs;  // 16B granules, 16 per row

    int s0 = rptr[r0];
    int n0 = rptr[r0 + 1] - s0;
    int s1 = 0, n1 = 0;
    if (has1) { s1 = rptr[r1]; n1 = rptr[r1 + 1] - s1; }

    int cc0 = (lane < n0) ? csr_col[s0 + lane] : N;   // pad -> zero row
    int cc1 = (has1 && lane < n1) ? csr_col[s1 + lane] : N;
    float sd0 = dvals[cc0];                           // dvals[N] = 0
    float sd1 = dvals[cc1];
    uint4 vs0 = xsv[(size_t)r0 * 16 + sl];
    uint4 vs1 = xsv[(size_t)(has1 ? r1 : N) * 16 + sl];

    float a0[8] = {0.f, 0.f, 0.f, 0.f, 0.f, 0.f, 0.f, 0.f};
    float a1[8] = {0.f, 0.f, 0.f, 0.f, 0.f, 0.f, 0.f, 0.f};
    int nf0 = (n0 < 64) ? n0 : 64;
    int nf1 = (n1 < 64) ? n1 : 64;
    int jm0 = (nf0 + 15) >> 4;                 // >= 1
    int jm1 = (nf1 + 15) >> 4;                 // 0 if !has1 possible? n1>=1 when has1
    if (!has1) jm1 = 0;
    int jmax = (jm0 > jm1) ? jm0 : jm1;

    for (int j = 0; j < jmax; ++j) {
        int base = j * 16 + grp;               // all shuffle idx < 64
        bool do0 = (j < jm0), do1 = (j < jm1); // wave-uniform
        uint4 u0, u1, u2, u3, w0, w1, w2, w3;
        if (do0) {
            int c0 = __shfl(cc0, base),      c1 = __shfl(cc0, base + 4);
            int c2 = __shfl(cc0, base + 8),  c3 = __shfl(cc0, base + 12);
            u0 = xsv[(size_t)c0 * 16 + sl];
            u1 = xsv[(size_t)c1 * 16 + sl];
            u2 = xsv[(size_t)c2 * 16 + sl];
            u3 = xsv[(size_t)c3 * 16 + sl];
        }
        if (do1) {
            int c0 = __shfl(cc1, base),      c1 = __shfl(cc1, base + 4);
            int c2 = __shfl(cc1, base + 8),  c3 = __shfl(cc1, base + 12);
            w0 = xsv[(size_t)c0 * 16 + sl];
            w1 = xsv[(size_t)c1 * 16 + sl];
            w2 = xsv[(size_t)c2 * 16 + sl];
            w3 = xsv[(size_t)c3 * 16 + sl];
        }
        __builtin_amdgcn_sched_barrier(0);     // loads above, math below
        if (do0) { ACC8(a0, u0); ACC8(a0, u1); ACC8(a0, u2); ACC8(a0, u3); }
        if (do1) { ACC8(a1, w0); ACC8(a1, w1); ACC8(a1, w2); ACC8(a1, w3); }
    }
    if (__builtin_expect(n0 > 64, 0)) {        // pathological high-degree tail
        for (int idx = 64 + grp; idx < n0; idx += 4) {
            int cc = csr_col[s0 + idx];
            uint4 v = xsv[(size_t)cc * 16 + sl];
            ACC8(a0, v);
        }
        for (int idx = 64 + lane; idx < n0; idx += 64)
            sd0 += dvals[csr_col[s0 + idx]];
    }
    if (__builtin_expect(n1 > 64, 0)) {
        for (int idx = 64 + grp; idx < n1; idx += 4) {
            int cc = csr_col[s1 + idx];
            uint4 v = xsv[(size_t)cc * 16 + sl];
            ACC8(a1, v);
        }
        for (int idx = 64 + lane; idx < n1; idx += 64)
            sd1 += dvals[csr_col[s1 + idx]];
    }
    if (grp == 0) { ACC8(a0, vs0); ACC8(a1, vs1); }  // self-loop terms (once)

    #pragma unroll
    for (int q = 0; q < 8; ++q) {
        a0[q] += __shfl_xor(a0[q], 16);
        a0[q] += __shfl_xor(a0[q], 32);
        a1[q] += __shfl_xor(a1[q], 16);
        a1[q] += __shfl_xor(a1[q], 32);
    }
    #pragma unroll
    for (int m = 1; m < 64; m <<= 1) {
        sd0 += __shfl_xor(sd0, m);
        sd1 += __shfl_xor(sd1, m);
    }

    float dr0 = dvals[r0];
    float dr1 = has1 ? dvals[r1] : 0.f;
    if (grp < 2) {           // groups 0,1 -> row 0 halves
        float4 o = (grp == 0) ? make_float4(a0[0], a0[1], a0[2], a0[3])
                              : make_float4(a0[4], a0[5], a0[6], a0[7]);
        o.x *= dr0; o.y *= dr0; o.z *= dr0; o.w *= dr0;
        ((float4*)(y + (size_t)r0 * D))[sl * 2 + grp] = o;
    } else if (has1) {       // groups 2,3 -> row 1 halves
        float4 o = (grp == 2) ? make_float4(a1[0], a1[1], a1[2], a1[3])
                              : make_float4(a1[4], a1[5], a1[6], a1[7]);
        o.x *= dr1; o.y *= dr1; o.z *= dr1; o.w *= dr1;
        ((float4*)(y + (size_t)r1 * D))[sl * 2 + (grp - 2)] = o;
    }
    if (lane == 0) ssum[r0] = dr0 * (dr0 + sd0);
    if (lane == 32 && has1) ssum[r1] = dr1 * (dr1 + sd1);
}

#define LDSW 136  // padded LDS stride for W planes (2-way bank conflict = free)

// MFMA GEMM (bf16x3 split): out[i][:] = y[i][:] @ W^T + ssum[i]*b, in place.
// W planes copied from the precomputed bf16 arrays (no per-block conversion).
__global__ __launch_bounds__(256, 2) void k_gemm(const unsigned short* __restrict__ Wbh,
                                                 const unsigned short* __restrict__ Wbl,
                                                 const float* __restrict__ b,
                                                 const float* __restrict__ ssum,
                                                 float* yo, int N) {
    __shared__ unsigned short Whi[128 * LDSW];
    __shared__ unsigned short Wlo[128 * LDSW];
    __shared__ float bs[D];
    int t = threadIdx.x;
    #pragma unroll
    for (int i = 0; i < 16; ++i) {
        int idx4 = i * 256 + t;          // ushort4 index, 4096 total
        int r = idx4 >> 5;
        int c = (idx4 & 31) * 4;
        ((ushort4*)&Whi[r * LDSW + c])[0] = ((const ushort4*)Wbh)[idx4];
        ((ushort4*)&Wlo[r * LDSW + c])[0] = ((const ushort4*)Wbl)[idx4];
    }
    if (t < D) bs[t] = b[t];
    __syncthreads();

    int wave = t >> 6, lane = t & 63;
    int quad = lane >> 4, mrow = lane & 15;
    int row_base = blockIdx.x * 128 + wave * 32;

    bf16x8 Ahi[2][4], Alo[2][4];
    #pragma unroll
    for (int s = 0; s < 2; ++s) {
        int grow = row_base + s * 16 + mrow;
        bool ok = grow < N;
        const float* yrow = yo + (size_t)(ok ? grow : 0) * D;
        #pragma unroll
        for (int kk = 0; kk < 4; ++kk) {
            int k0 = kk * 32 + quad * 8;
            float4 f0 = ok ? ((const float4*)(yrow + k0))[0] : make_float4(0, 0, 0, 0);
            float4 f1 = ok ? ((const float4*)(yrow + k0))[1] : make_float4(0, 0, 0, 0);
            float fv[8] = {f0.x, f0.y, f0.z, f0.w, f1.x, f1.y, f1.z, f1.w};
            #pragma unroll
            for (int j = 0; j < 8; ++j) {
                unsigned short h = f2bf(fv[j]);
                Ahi[s][kk][j] = (short)h;
                Alo[s][kk][j] = (short)f2bf(fv[j] - bf2f(h));
            }
        }
    }

    f32x4 acc[2][8];
    #pragma unroll
    for (int s = 0; s < 2; ++s)
        #pragma unroll
        for (int ct = 0; ct < 8; ++ct)
            acc[s][ct] = (f32x4){0.f, 0.f, 0.f, 0.f};

    #pragma unroll
    for (int ct = 0; ct < 8; ++ct) {
        int wrow = ct * 16 + mrow;
        #pragma unroll
        for (int kk = 0; kk < 4; ++kk) {
            int off = wrow * LDSW + kk * 32 + quad * 8;
            bf16x8 Bhi = *(const bf16x8*)&Whi[off];
            bf16x8 Blo = *(const bf16x8*)&Wlo[off];
            #pragma unroll
            for (int s = 0; s < 2; ++s) {
                acc[s][ct] = __builtin_amdgcn_mfma_f32_16x16x32_bf16(Ahi[s][kk], Bhi, acc[s][ct], 0, 0, 0);
                acc[s][ct] = __builtin_amdgcn_mfma_f32_16x16x32_bf16(Alo[s][kk], Bhi, acc[s][ct], 0, 0, 0);
                acc[s][ct] = __builtin_amdgcn_mfma_f32_16x16x32_bf16(Ahi[s][kk], Blo, acc[s][ct], 0, 0, 0);
            }
        }
    }

    #pragma unroll
    for (int s = 0; s < 2; ++s) {
        #pragma unroll
        for (int r = 0; r < 4; ++r) {
            int grow = row_base + s * 16 + quad * 4 + r;
            if (grow < N) {
                float sv = ssum[grow];
                #pragma unroll
                for (int ct = 0; ct < 8; ++ct) {
                    int col = ct * 16 + mrow;
                    yo[(size_t)grow * D + col] = acc[s][ct][r] + sv * bs[col];
                }
            }
        }
    }
}

extern "C" void kernel_launch(void* const* d_in, const int* in_sizes, int n_in,
                              void* d_out, int out_size, void* d_ws, size_t ws_size,
                              hipStream_t stream) {
    const float* x  = (const float*)d_in[0];
    const int*   ei = (const int*)d_in[1];
    const float* W  = (const float*)d_in[2];
    const float* b  = (const float*)d_in[3];
    float* out = (float*)d_out;
    int N = in_sizes[0] / D;
    int E = in_sizes[1] / 2;
    int NB = (N + BROWS - 1) / BROWS;        // 196
    int NCH = (E + CHUNK - 1) / CHUNK;       // 391

    int*            gcur    = (int*)d_ws;                // NBMAX
    int*            rptr    = gcur + NBMAX;              // N+1
    float*          dvals   = (float*)(rptr + N + 1);    // N+1 (dvals[N]=0 pad)
    float*          ssum    = dvals + N + 1;             // N
    int*            csr_col = (int*)(ssum + N);          // E+64 (uncond read pad)
    unsigned*       ebuf    = (unsigned*)(csr_col + E + 64);  // NB*CAP
    unsigned short* Wbh     = (unsigned short*)(ebuf + (size_t)NB * CAP);  // 16384
    unsigned short* Wbl     = Wbh + D * D;                                  // 16384
    uintptr_t xs_addr = (uintptr_t)(Wbl + D * D);
    xs_addr = (xs_addr + 15) & ~(uintptr_t)15;
    unsigned short* xs = (unsigned short*)xs_addr;  // (N+1)*D bf16; row N zeros

    hipMemsetAsync(gcur, 0, NBMAX * sizeof(int), stream);
    k_bin<<<NCH, 512, 0, stream>>>(ei, ei + E, E, gcur, ebuf, W, Wbh, Wbl);
    k_group<<<NB, 1024, 0, stream>>>(gcur, ebuf, x, N, NB, dvals, rptr, csr_col, xs);
    k_rows<<<(N + 7) / 8, 256, 0, stream>>>(xs, rptr, csr_col, dvals, ssum, out, N);
    k_gemm<<<(N + 127) / 128, 256, 0, stream>>>(Wbh, Wbl, b, ssum, out, N);
}

// Round 7
// 275.345 us; speedup vs baseline: 1.0143x; 1.0143x over previous
//
#include <hip/hip_runtime.h>

#define D 128
#define BROWS 512       // rows per coarse bucket
#define LOGB 9
#define NBMAX 256       // max buckets (N <= 131072)
#define CAP 9216        // entries per bucket region (mean 8192, +11 sigma)
#define CHUNK 4096      // edges per k_bin chunk

typedef __attribute__((ext_vector_type(8))) short bf16x8;
typedef __attribute__((ext_vector_type(4))) float f32x4;

__device__ inline unsigned short f2bf(float f) {
    unsigned u = __float_as_uint(f);
    u += 0x7FFFu + ((u >> 16) & 1u);
    return (unsigned short)(u >> 16);
}
__device__ inline float bf2f(unsigned short h) {
    return __uint_as_float((unsigned)h << 16);
}
__device__ inline float bflo(unsigned u) { return __uint_as_float(u << 16); }
__device__ inline float bfhi(unsigned u) { return __uint_as_float(u & 0xFFFF0000u); }

// Bin edges into NB coarse buckets; packed entry = (local_row<<17)|col.
// Blocks 0-7 additionally pre-convert W to bf16 hi/lo (once for the pipeline).
__global__ __launch_bounds__(512) void k_bin(const int* __restrict__ row,
                                             const int* __restrict__ col,
                                             int E, int* __restrict__ gcur,
                                             unsigned* __restrict__ ebuf,
                                             const float* __restrict__ W,
                                             unsigned short* __restrict__ Wbh,
                                             unsigned short* __restrict__ Wbl) {
    __shared__ int lhist[NBMAX];
    __shared__ int sc[NBMAX];
    __shared__ int gbase[NBMAX];
    __shared__ unsigned sstage[CHUNK];
    __shared__ int sdest[CHUNK];
    int t = threadIdx.x;
    if (blockIdx.x < 8) {   // W -> bf16 hi/lo, 2048 elements per block
        int base = blockIdx.x * 2048 + t;
        #pragma unroll
        for (int i = 0; i < 4; ++i) {
            int idx = base + i * 512;
            float wv = W[idx];
            unsigned short h = f2bf(wv);
            Wbh[idx] = h;
            Wbl[idx] = f2bf(wv - bf2f(h));
        }
    }
    int base = blockIdx.x * CHUNK;
    if (t < NBMAX) lhist[t] = 0;
    __syncthreads();
    int b[8], p[8]; unsigned pk[8];
    #pragma unroll
    for (int i = 0; i < 8; ++i) {
        int idx = base + i * 512 + t;
        if (idx < E) {
            int r = row[idx], c = col[idx];
            b[i] = r >> LOGB;
            pk[i] = ((unsigned)(r & (BROWS - 1)) << 17) | (unsigned)c;
            p[i] = atomicAdd(&lhist[b[i]], 1);
        } else b[i] = -1;
    }
    __syncthreads();
    if (t < 64) {   // wave-0 scan, 4 bins per lane (256 bins)
        int a0 = lhist[4*t], a1 = lhist[4*t+1], a2 = lhist[4*t+2], a3 = lhist[4*t+3];
        int s = a0 + a1 + a2 + a3;
        int incl = s;
        #pragma unroll
        for (int m = 1; m < 64; m <<= 1) {
            int tmp = __shfl_up(incl, m);
            if (t >= m) incl += tmp;
        }
        int excl = incl - s;
        sc[4*t] = excl; sc[4*t+1] = excl + a0;
        sc[4*t+2] = excl + a0 + a1; sc[4*t+3] = excl + a0 + a1 + a2;
        if (a0 > 0) gbase[4*t]   = atomicAdd(&gcur[4*t],   a0);
        if (a1 > 0) gbase[4*t+1] = atomicAdd(&gcur[4*t+1], a1);
        if (a2 > 0) gbase[4*t+2] = atomicAdd(&gcur[4*t+2], a2);
        if (a3 > 0) gbase[4*t+3] = atomicAdd(&gcur[4*t+3], a3);
    }
    __syncthreads();
    #pragma unroll
    for (int i = 0; i < 8; ++i) {
        if (b[i] >= 0) {
            int lidx = sc[b[i]] + p[i];
            int rel = gbase[b[i]] + p[i];
            sstage[lidx] = pk[i];
            sdest[lidx] = (rel < CAP) ? (b[i] * CAP + rel) : -1;
        }
    }
    __syncthreads();
    int total = sc[NBMAX - 1] + lhist[NBMAX - 1];
    for (int i = t; i < total; i += 512) {
        int d = sdest[i];
        if (d >= 0) ebuf[d] = sstage[i];
    }
}

// One block per bucket: stage bucket in LDS, degree hist + scan -> dvals/rptr,
// counting-sort csr_col, then cast this bucket's x rows to pre-scaled bf16
// (merged k_cast — dvals already in LDS).
__global__ __launch_bounds__(1024) void k_group(const int* __restrict__ gcur,
                                                const unsigned* __restrict__ ebuf,
                                                const float* __restrict__ x,
                                                int N, int NBK,
                                                float* __restrict__ dvals,
                                                int* __restrict__ rptr,
                                                int* __restrict__ csr_col,
                                                unsigned short* __restrict__ xs) {
    __shared__ unsigned sebuf[CAP];   // 36 KB
    __shared__ int lhist[BROWS];      // hist, then cursor
    __shared__ float sdl[BROWS];      // per-row d for the cast phase
    __shared__ int wtot[8];
    __shared__ int woff[8];
    __shared__ int sebase;
    int bkt = blockIdx.x, t = threadIdx.x;
    int cnt = gcur[bkt]; if (cnt > CAP) cnt = CAP;
    if (t < 64) {
        int acc = 0;
        for (int i = t; i < bkt; i += 64) {
            int g = gcur[i];
            acc += (g > CAP) ? CAP : g;
        }
        #pragma unroll
        for (int m = 1; m < 64; m <<= 1) acc += __shfl_xor(acc, m);
        if (t == 0) sebase = acc;
    }
    if (t < BROWS) lhist[t] = 0;
    __syncthreads();
    const unsigned* ep = ebuf + (size_t)bkt * CAP;
    for (int i = t; i < cnt; i += 1024) {
        unsigned e = ep[i];
        sebuf[i] = e;
        atomicAdd(&lhist[e >> 17], 1);
    }
    __syncthreads();
    int lane = t & 63, wv = t >> 6;
    int v = 0, incl = 0;
    if (t < BROWS) {    // 8 waves scan 512 degrees
        v = lhist[t];
        incl = v;
        #pragma unroll
        for (int m = 1; m < 64; m <<= 1) {
            int tmp = __shfl_up(incl, m);
            if (lane >= m) incl += tmp;
        }
        if (lane == 63) wtot[wv] = incl;
    }
    __syncthreads();
    if (t < 8) {
        int w = wtot[t];
        int wincl = w;
        #pragma unroll
        for (int m = 1; m < 8; m <<= 1) {
            int tmp = __shfl_up(wincl, m);
            if (t >= m) wincl += tmp;
        }
        woff[t] = wincl - w;
    }
    __syncthreads();
    int ebase = sebase;
    if (t < BROWS) {
        int excl = woff[wv] + incl - v;
        int r = (bkt << LOGB) + t;
        float dl = rsqrtf((float)v);
        if (r < N) {
            rptr[r] = ebase + excl;
            dvals[r] = dl;
        }
        sdl[t] = dl;
        lhist[t] = excl;              // becomes running cursor
    }
    if (bkt == NBK - 1 && t == 0) rptr[N] = ebase + cnt;
    if (bkt == 0 && t == 0) dvals[N] = 0.f;   // pad target for unconditional sd
    __syncthreads();
    for (int i = t; i < cnt; i += 1024) {
        unsigned e = sebuf[i];
        int rr = (int)(e >> 17);
        int p = atomicAdd(&lhist[rr], 1);
        csr_col[ebase + p] = (int)(e & 0x1FFFFu);
    }
    // cast phase: xs[r][:] = bf16(d[r] * x[r][:]) for this bucket's rows
    int rb = bkt << LOGB;
    const float4* x4 = (const float4*)x;
    for (int idx = t; idx < BROWS * 32; idx += 1024) {
        int rl = idx >> 5;
        int r = rb + rl;
        if (r < N) {
            float4 vv = x4[(size_t)r * 32 + (idx & 31)];
            float d = sdl[rl];
            ushort4 o = make_ushort4(f2bf(d * vv.x), f2bf(d * vv.y),
                                     f2bf(d * vv.z), f2bf(d * vv.w));
            ((ushort4*)xs)[(size_t)r * 32 + (idx & 31)] = o;
        }
    }
    if (bkt == 0 && t < 64)   // zero row N (gather pad target)
        ((unsigned*)(xs + (size_t)N * D))[t] = 0u;
}

#define ACC8(v) do { \
    a[0] += bflo((v).x); a[1] += bfhi((v).x); \
    a[2] += bflo((v).y); a[3] += bfhi((v).y); \
    a[4] += bflo((v).z); a[5] += bfhi((v).z); \
    a[6] += bflo((v).w); a[7] += bfhi((v).w); } while (0)

// Wave per row, R1 geometry (best measured: 77 us). 16-edge chunks, 4
// unconditional zero-row-padded gathers per chunk. Robustness vs R1:
// (a) loads unconditional -> nothing for a register allocator to serialize
//     behind predication (R2 container: VGPR 24 -> 86 us);
// (b) sched_group_barrier pins "4 VMEM then the ACC VALU block" INSIDE each
//     iteration, while leaving the scheduler free to pipeline next-chunk
//     shuffles/loads across iterations (R5/R6 lesson: sched_barrier(0)
//     blocked that pipelining -> 88/96 us).
__global__ __launch_bounds__(256) void k_rows(const unsigned short* __restrict__ xs,
                                              const int* __restrict__ rptr,
                                              const int* __restrict__ csr_col,
                                              const float* __restrict__ dvals,
                                              float* __restrict__ ssum,
                                              float* __restrict__ y, int N) {
    int wid = (blockIdx.x * blockDim.x + threadIdx.x) >> 6;
    if (wid >= N) return;
    int lane = threadIdx.x & 63;
    int grp = lane >> 4, sl = lane & 15;
    int s = rptr[wid];
    int n = rptr[wid + 1] - s;
    const uint4* xsv = (const uint4*)xs;  // 16B granules, 16 per row

    int cc = csr_col[s + lane];           // unconditional (csr_col padded +64)
    int ccreg = (lane < n) ? cc : N;      // pad lanes -> zero row
    float sd = dvals[ccreg];              // dvals[N] = 0 -> pads contribute 0
    uint4 vself = xsv[(size_t)wid * 16 + sl];

    float a[8] = {0.f, 0.f, 0.f, 0.f, 0.f, 0.f, 0.f, 0.f};
    int nf = (n < 64) ? n : 64;
    for (int k0 = 0; k0 < nf; k0 += 16) {
        int i0 = k0 + grp;                // shuffle idx < 64 always
        int c0 = __shfl(ccreg, i0);
        int c1 = __shfl(ccreg, i0 + 4);
        int c2 = __shfl(ccreg, i0 + 8);
        int c3 = __shfl(ccreg, i0 + 12);
        uint4 v0 = xsv[(size_t)c0 * 16 + sl];
        uint4 v1 = xsv[(size_t)c1 * 16 + sl];
        uint4 v2 = xsv[(size_t)c2 * 16 + sl];
        uint4 v3 = xsv[(size_t)c3 * 16 + sl];
        __builtin_amdgcn_sched_group_barrier(0x020, 4, 0);  // 4 VMEM reads first
        ACC8(v0); ACC8(v1); ACC8(v2); ACC8(v3);
        __builtin_amdgcn_sched_group_barrier(0x002, 64, 0); // then the ACC block
    }
    if (__builtin_expect(n > 64, 0)) {   // pathological high-degree fallback
        for (int idx = 64 + grp; idx < n; idx += 4) {
            int c = csr_col[s + idx];
            uint4 v = xsv[(size_t)c * 16 + sl];
            ACC8(v);
        }
        for (int idx = 64 + lane; idx < n; idx += 64)
            sd += dvals[csr_col[s + idx]];
    }
    if (grp == 0) ACC8(vself);  // self-loop: d[r]^2 x[r] = d[r] * xs[r]

    #pragma unroll
    for (int j = 0; j < 8; ++j) {
        a[j] += __shfl_xor(a[j], 16);
        a[j] += __shfl_xor(a[j], 32);
    }
    #pragma unroll
    for (int m = 1; m < 64; m <<= 1) sd += __shfl_xor(sd, m);

    float dr = dvals[wid];
    if (grp < 2) {
        float4 o = (grp == 0) ? make_float4(a[0], a[1], a[2], a[3])
                              : make_float4(a[4], a[5], a[6], a[7]);
        o.x *= dr; o.y *= dr; o.z *= dr; o.w *= dr;
        ((float4*)(y + (size_t)wid * D))[sl * 2 + grp] = o;
    }
    if (lane == 0) ssum[wid] = dr * (dr + sd);
}

#define LDSW 136  // padded LDS stride for W planes (2-way bank conflict = free)

// MFMA GEMM (bf16x3 split): out[i][:] = y[i][:] @ W^T + ssum[i]*b, in place.
// W planes copied from the precomputed bf16 arrays (no per-block conversion).
__global__ __launch_bounds__(256, 2) void k_gemm(const unsigned short* __restrict__ Wbh,
                                                 const unsigned short* __restrict__ Wbl,
                                                 const float* __restrict__ b,
                                                 const float* __restrict__ ssum,
                                                 float* yo, int N) {
    __shared__ unsigned short Whi[128 * LDSW];
    __shared__ unsigned short Wlo[128 * LDSW];
    __shared__ float bs[D];
    int t = threadIdx.x;
    #pragma unroll
    for (int i = 0; i < 16; ++i) {
        int idx4 = i * 256 + t;          // ushort4 index, 4096 total
        int r = idx4 >> 5;
        int c = (idx4 & 31) * 4;
        ((ushort4*)&Whi[r * LDSW + c])[0] = ((const ushort4*)Wbh)[idx4];
        ((ushort4*)&Wlo[r * LDSW + c])[0] = ((const ushort4*)Wbl)[idx4];
    }
    if (t < D) bs[t] = b[t];
    __syncthreads();

    int wave = t >> 6, lane = t & 63;
    int quad = lane >> 4, mrow = lane & 15;
    int row_base = blockIdx.x * 128 + wave * 32;

    bf16x8 Ahi[2][4], Alo[2][4];
    #pragma unroll
    for (int s = 0; s < 2; ++s) {
        int grow = row_base + s * 16 + mrow;
        bool ok = grow < N;
        const float* yrow = yo + (size_t)(ok ? grow : 0) * D;
        #pragma unroll
        for (int kk = 0; kk < 4; ++kk) {
            int k0 = kk * 32 + quad * 8;
            float4 f0 = ok ? ((const float4*)(yrow + k0))[0] : make_float4(0, 0, 0, 0);
            float4 f1 = ok ? ((const float4*)(yrow + k0))[1] : make_float4(0, 0, 0, 0);
            float fv[8] = {f0.x, f0.y, f0.z, f0.w, f1.x, f1.y, f1.z, f1.w};
            #pragma unroll
            for (int j = 0; j < 8; ++j) {
                unsigned short h = f2bf(fv[j]);
                Ahi[s][kk][j] = (short)h;
                Alo[s][kk][j] = (short)f2bf(fv[j] - bf2f(h));
            }
        }
    }

    f32x4 acc[2][8];
    #pragma unroll
    for (int s = 0; s < 2; ++s)
        #pragma unroll
        for (int ct = 0; ct < 8; ++ct)
            acc[s][ct] = (f32x4){0.f, 0.f, 0.f, 0.f};

    #pragma unroll
    for (int ct = 0; ct < 8; ++ct) {
        int wrow = ct * 16 + mrow;
        #pragma unroll
        for (int kk = 0; kk < 4; ++kk) {
            int off = wrow * LDSW + kk * 32 + quad * 8;
            bf16x8 Bhi = *(const bf16x8*)&Whi[off];
            bf16x8 Blo = *(const bf16x8*)&Wlo[off];
            #pragma unroll
            for (int s = 0; s < 2; ++s) {
                acc[s][ct] = __builtin_amdgcn_mfma_f32_16x16x32_bf16(Ahi[s][kk], Bhi, acc[s][ct], 0, 0, 0);
                acc[s][ct] = __builtin_amdgcn_mfma_f32_16x16x32_bf16(Alo[s][kk], Bhi, acc[s][ct], 0, 0, 0);
                acc[s][ct] = __builtin_amdgcn_mfma_f32_16x16x32_bf16(Ahi[s][kk], Blo, acc[s][ct], 0, 0, 0);
            }
        }
    }

    #pragma unroll
    for (int s = 0; s < 2; ++s) {
        #pragma unroll
        for (int r = 0; r < 4; ++r) {
            int grow = row_base + s * 16 + quad * 4 + r;
            if (grow < N) {
                float sv = ssum[grow];
                #pragma unroll
                for (int ct = 0; ct < 8; ++ct) {
                    int col = ct * 16 + mrow;
                    yo[(size_t)grow * D + col] = acc[s][ct][r] + sv * bs[col];
                }
            }
        }
    }
}

extern "C" void kernel_launch(void* const* d_in, const int* in_sizes, int n_in,
                              void* d_out, int out_size, void* d_ws, size_t ws_size,
                              hipStream_t stream) {
    const float* x  = (const float*)d_in[0];
    const int*   ei = (const int*)d_in[1];
    const float* W  = (const float*)d_in[2];
    const float* b  = (const float*)d_in[3];
    float* out = (float*)d_out;
    int N = in_sizes[0] / D;
    int E = in_sizes[1] / 2;
    int NB = (N + BROWS - 1) / BROWS;        // 196
    int NCH = (E + CHUNK - 1) / CHUNK;       // 391

    int*            gcur    = (int*)d_ws;                // NBMAX
    int*            rptr    = gcur + NBMAX;              // N+1
    float*          dvals   = (float*)(rptr + N + 1);    // N+1 (dvals[N]=0 pad)
    float*          ssum    = dvals + N + 1;             // N
    int*            csr_col = (int*)(ssum + N);          // E+64 (uncond read pad)
    unsigned*       ebuf    = (unsigned*)(csr_col + E + 64);  // NB*CAP
    unsigned short* Wbh     = (unsigned short*)(ebuf + (size_t)NB * CAP);  // 16384
    unsigned short* Wbl     = Wbh + D * D;                                  // 16384
    uintptr_t xs_addr = (uintptr_t)(Wbl + D * D);
    xs_addr = (xs_addr + 15) & ~(uintptr_t)15;
    unsigned short* xs = (unsigned short*)xs_addr;  // (N+1)*D bf16; row N zeros

    hipMemsetAsync(gcur, 0, NBMAX * sizeof(int), stream);
    k_bin<<<NCH, 512, 0, stream>>>(ei, ei + E, E, gcur, ebuf, W, Wbh, Wbl);
    k_group<<<NB, 1024, 0, stream>>>(gcur, ebuf, x, N, NB, dvals, rptr, csr_col, xs);
    k_rows<<<(N + 3) / 4, 256, 0, stream>>>(xs, rptr, csr_col, dvals, ssum, out, N);
    k_gemm<<<(N + 127) / 128, 256, 0, stream>>>(Wbh, Wbl, b, ssum, out, N);
}

// Round 8
// 248.878 us; speedup vs baseline: 1.1222x; 1.1063x over previous
//
#include <hip/hip_runtime.h>

#define D 128
#define BROWS 512       // rows per coarse bucket
#define LOGB 9
#define NBMAX 256       // max buckets (N <= 131072)
#define CAP 9216        // entries per bucket region (mean 8192, +11 sigma)
#define CHUNK 4096      // edges per k_bin chunk
#define LDSW 136        // padded LDS stride for W planes

typedef __attribute__((ext_vector_type(8))) short bf16x8;
typedef __attribute__((ext_vector_type(4))) float f32x4;

__device__ inline unsigned short f2bf(float f) {
    unsigned u = __float_as_uint(f);
    u += 0x7FFFu + ((u >> 16) & 1u);
    return (unsigned short)(u >> 16);
}
__device__ inline float bf2f(unsigned short h) {
    return __uint_as_float((unsigned)h << 16);
}
__device__ inline float bflo(unsigned u) { return __uint_as_float(u << 16); }
__device__ inline float bfhi(unsigned u) { return __uint_as_float(u & 0xFFFF0000u); }

// Bin edges into NB coarse buckets; packed entry = (local_row<<17)|col.
// Blocks 0-7 additionally pre-convert W to bf16 hi/lo (once for the pipeline).
__global__ __launch_bounds__(512) void k_bin(const int* __restrict__ row,
                                             const int* __restrict__ col,
                                             int E, int* __restrict__ gcur,
                                             unsigned* __restrict__ ebuf,
                                             const float* __restrict__ W,
                                             unsigned short* __restrict__ Wbh,
                                             unsigned short* __restrict__ Wbl) {
    __shared__ int lhist[NBMAX];
    __shared__ int sc[NBMAX];
    __shared__ int gbase[NBMAX];
    __shared__ unsigned sstage[CHUNK];
    __shared__ int sdest[CHUNK];
    int t = threadIdx.x;
    if (blockIdx.x < 8) {   // W -> bf16 hi/lo, 2048 elements per block
        int base = blockIdx.x * 2048 + t;
        #pragma unroll
        for (int i = 0; i < 4; ++i) {
            int idx = base + i * 512;
            float wv = W[idx];
            unsigned short h = f2bf(wv);
            Wbh[idx] = h;
            Wbl[idx] = f2bf(wv - bf2f(h));
        }
    }
    int base = blockIdx.x * CHUNK;
    if (t < NBMAX) lhist[t] = 0;
    __syncthreads();
    int b[8], p[8]; unsigned pk[8];
    #pragma unroll
    for (int i = 0; i < 8; ++i) {
        int idx = base + i * 512 + t;
        if (idx < E) {
            int r = row[idx], c = col[idx];
            b[i] = r >> LOGB;
            pk[i] = ((unsigned)(r & (BROWS - 1)) << 17) | (unsigned)c;
            p[i] = atomicAdd(&lhist[b[i]], 1);
        } else b[i] = -1;
    }
    __syncthreads();
    if (t < 64) {   // wave-0 scan, 4 bins per lane (256 bins)
        int a0 = lhist[4*t], a1 = lhist[4*t+1], a2 = lhist[4*t+2], a3 = lhist[4*t+3];
        int s = a0 + a1 + a2 + a3;
        int incl = s;
        #pragma unroll
        for (int m = 1; m < 64; m <<= 1) {
            int tmp = __shfl_up(incl, m);
            if (t >= m) incl += tmp;
        }
        int excl = incl - s;
        sc[4*t] = excl; sc[4*t+1] = excl + a0;
        sc[4*t+2] = excl + a0 + a1; sc[4*t+3] = excl + a0 + a1 + a2;
        if (a0 > 0) gbase[4*t]   = atomicAdd(&gcur[4*t],   a0);
        if (a1 > 0) gbase[4*t+1] = atomicAdd(&gcur[4*t+1], a1);
        if (a2 > 0) gbase[4*t+2] = atomicAdd(&gcur[4*t+2], a2);
        if (a3 > 0) gbase[4*t+3] = atomicAdd(&gcur[4*t+3], a3);
    }
    __syncthreads();
    #pragma unroll
    for (int i = 0; i < 8; ++i) {
        if (b[i] >= 0) {
            int lidx = sc[b[i]] + p[i];
            int rel = gbase[b[i]] + p[i];
            sstage[lidx] = pk[i];
            sdest[lidx] = (rel < CAP) ? (b[i] * CAP + rel) : -1;
        }
    }
    __syncthreads();
    int total = sc[NBMAX - 1] + lhist[NBMAX - 1];
    for (int i = t; i < total; i += 512) {
        int d = sdest[i];
        if (d >= 0) ebuf[d] = sstage[i];
    }
}

// One block per bucket: stage bucket in LDS, degree hist + scan -> dvals/rptr,
// counting-sort csr_col. (Cast phase moved into k_gc's epilogue.)
__global__ __launch_bounds__(1024) void k_group(const int* __restrict__ gcur,
                                                const unsigned* __restrict__ ebuf,
                                                int N, int NBK,
                                                float* __restrict__ dvals,
                                                int* __restrict__ rptr,
                                                int* __restrict__ csr_col,
                                                unsigned short* __restrict__ Hs) {
    __shared__ unsigned sebuf[CAP];   // 36 KB
    __shared__ int lhist[BROWS];      // hist, then cursor
    __shared__ int wtot[8];
    __shared__ int woff[8];
    __shared__ int sebase;
    int bkt = blockIdx.x, t = threadIdx.x;
    int cnt = gcur[bkt]; if (cnt > CAP) cnt = CAP;
    if (t < 64) {
        int acc = 0;
        for (int i = t; i < bkt; i += 64) {
            int g = gcur[i];
            acc += (g > CAP) ? CAP : g;
        }
        #pragma unroll
        for (int m = 1; m < 64; m <<= 1) acc += __shfl_xor(acc, m);
        if (t == 0) sebase = acc;
    }
    if (t < BROWS) lhist[t] = 0;
    __syncthreads();
    const unsigned* ep = ebuf + (size_t)bkt * CAP;
    for (int i = t; i < cnt; i += 1024) {
        unsigned e = ep[i];
        sebuf[i] = e;
        atomicAdd(&lhist[e >> 17], 1);
    }
    __syncthreads();
    int lane = t & 63, wv = t >> 6;
    int v = 0, incl = 0;
    if (t < BROWS) {    // 8 waves scan 512 degrees
        v = lhist[t];
        incl = v;
        #pragma unroll
        for (int m = 1; m < 64; m <<= 1) {
            int tmp = __shfl_up(incl, m);
            if (lane >= m) incl += tmp;
        }
        if (lane == 63) wtot[wv] = incl;
    }
    __syncthreads();
    if (t < 8) {
        int w = wtot[t];
        int wincl = w;
        #pragma unroll
        for (int m = 1; m < 8; m <<= 1) {
            int tmp = __shfl_up(wincl, m);
            if (t >= m) wincl += tmp;
        }
        woff[t] = wincl - w;
    }
    __syncthreads();
    int ebase = sebase;
    if (t < BROWS) {
        int excl = woff[wv] + incl - v;
        int r = (bkt << LOGB) + t;
        if (r < N) {
            rptr[r] = ebase + excl;
            dvals[r] = rsqrtf((float)v);
        }
        lhist[t] = excl;              // becomes running cursor
    }
    if (bkt == NBK - 1 && t == 0) rptr[N] = ebase + cnt;
    if (bkt == 0 && t == 0) dvals[N] = 0.f;   // pad slot
    if (bkt == 0 && t < 64)                    // zero row N of Hs (gather pad)
        ((unsigned*)(Hs + (size_t)N * D))[t] = 0u;
    __syncthreads();
    for (int i = t; i < cnt; i += 1024) {
        unsigned e = sebuf[i];
        int rr = (int)(e >> 17);
        int p = atomicAdd(&lhist[rr], 1);
        csr_col[ebase + p] = (int)(e & 0x1FFFFu);
    }
}

// GEMM-FIRST: Hs[r][:] = bf16(d_r * (x[r] @ W^T + b)).  Proven k_gemm body
// (bf16x3 MFMA) with A = x; epilogue scales by dvals, adds bias, casts bf16,
// stages in LDS (aliased onto the dead Whi plane) and writes coalesced 16B.
// After this, the gather kernel's output IS the final out:
//   out[r] = d_r * (sum_{c in N(r)} Hs[c] + Hs[r])
// which equals d*agg + d^2*h of the reference (bias included via h).
__global__ __launch_bounds__(256, 2) void k_gc(const float* __restrict__ x,
                                               const unsigned short* __restrict__ Wbh,
                                               const unsigned short* __restrict__ Wbl,
                                               const float* __restrict__ b,
                                               const float* __restrict__ dvals,
                                               unsigned short* __restrict__ Hs, int N) {
    __shared__ unsigned short Whi[128 * LDSW];   // 34.8 KB (reused as stage)
    __shared__ unsigned short Wlo[128 * LDSW];
    __shared__ float bs[D];
    int t = threadIdx.x;
    #pragma unroll
    for (int i = 0; i < 16; ++i) {
        int idx4 = i * 256 + t;          // ushort4 index, 4096 total
        int r = idx4 >> 5;
        int c = (idx4 & 31) * 4;
        ((ushort4*)&Whi[r * LDSW + c])[0] = ((const ushort4*)Wbh)[idx4];
        ((ushort4*)&Wlo[r * LDSW + c])[0] = ((const ushort4*)Wbl)[idx4];
    }
    if (t < D) bs[t] = b[t];
    __syncthreads();

    int wave = t >> 6, lane = t & 63;
    int quad = lane >> 4, mrow = lane & 15;
    int row_base = blockIdx.x * 128 + wave * 32;

    bf16x8 Ahi[2][4], Alo[2][4];
    #pragma unroll
    for (int s = 0; s < 2; ++s) {
        int grow = row_base + s * 16 + mrow;
        bool ok = grow < N;
        const float* xrow = x + (size_t)(ok ? grow : 0) * D;
        #pragma unroll
        for (int kk = 0; kk < 4; ++kk) {
            int k0 = kk * 32 + quad * 8;
            float4 f0 = ok ? ((const float4*)(xrow + k0))[0] : make_float4(0, 0, 0, 0);
            float4 f1 = ok ? ((const float4*)(xrow + k0))[1] : make_float4(0, 0, 0, 0);
            float fv[8] = {f0.x, f0.y, f0.z, f0.w, f1.x, f1.y, f1.z, f1.w};
            #pragma unroll
            for (int j = 0; j < 8; ++j) {
                unsigned short h = f2bf(fv[j]);
                Ahi[s][kk][j] = (short)h;
                Alo[s][kk][j] = (short)f2bf(fv[j] - bf2f(h));
            }
        }
    }

    f32x4 acc[2][8];
    #pragma unroll
    for (int s = 0; s < 2; ++s)
        #pragma unroll
        for (int ct = 0; ct < 8; ++ct)
            acc[s][ct] = (f32x4){0.f, 0.f, 0.f, 0.f};

    #pragma unroll
    for (int ct = 0; ct < 8; ++ct) {
        int wrow = ct * 16 + mrow;
        #pragma unroll
        for (int kk = 0; kk < 4; ++kk) {
            int off = wrow * LDSW + kk * 32 + quad * 8;
            bf16x8 Bhi = *(const bf16x8*)&Whi[off];
            bf16x8 Blo = *(const bf16x8*)&Wlo[off];
            #pragma unroll
            for (int s = 0; s < 2; ++s) {
                acc[s][ct] = __builtin_amdgcn_mfma_f32_16x16x32_bf16(Ahi[s][kk], Bhi, acc[s][ct], 0, 0, 0);
                acc[s][ct] = __builtin_amdgcn_mfma_f32_16x16x32_bf16(Alo[s][kk], Bhi, acc[s][ct], 0, 0, 0);
                acc[s][ct] = __builtin_amdgcn_mfma_f32_16x16x32_bf16(Ahi[s][kk], Blo, acc[s][ct], 0, 0, 0);
            }
        }
    }

    __syncthreads();                 // all waves done reading Whi/Wlo
    unsigned short* stage = Whi;     // alias: 128 x LDSW bf16 output tile
    #pragma unroll
    for (int s = 0; s < 2; ++s) {
        #pragma unroll
        for (int r = 0; r < 4; ++r) {
            int grow = row_base + s * 16 + quad * 4 + r;
            float dv = dvals[(grow < N) ? grow : N];   // dvals[N]=0
            int lrow = wave * 32 + s * 16 + quad * 4 + r;
            #pragma unroll
            for (int ct = 0; ct < 8; ++ct) {
                int col = ct * 16 + mrow;
                stage[lrow * LDSW + col] = f2bf(dv * (acc[s][ct][r] + bs[col]));
            }
        }
    }
    __syncthreads();
    for (int i = t; i < 128 * 16; i += 256) {   // 16B granules: 128 rows x 16
        int lrow = i >> 4;
        int g = i & 15;
        int grow = blockIdx.x * 128 + lrow;
        if (grow < N)
            ((uint4*)Hs)[(size_t)grow * 16 + g] =
                ((const uint4*)&stage[lrow * LDSW])[g];
    }
}

#define ACC8(v) do { \
    a[0] += bflo((v).x); a[1] += bfhi((v).x); \
    a[2] += bflo((v).y); a[3] += bfhi((v).y); \
    a[4] += bflo((v).z); a[5] += bfhi((v).z); \
    a[6] += bflo((v).w); a[7] += bfhi((v).w); } while (0)

// Wave per row over Hs, FINAL OUTPUT kernel. R1/R7 geometry (16-edge chunks,
// 4 gathers/batch), loads unconditional via zero-row padding, NO scheduling
// pragmas (R5-R7 lesson: every pinning attempt lost to the free scheduler).
// No per-edge dvals gather, no ssum — all folded into k_gc.
__global__ __launch_bounds__(256) void k_rows(const unsigned short* __restrict__ Hs,
                                              const int* __restrict__ rptr,
                                              const int* __restrict__ csr_col,
                                              const float* __restrict__ dvals,
                                              float* __restrict__ out, int N) {
    int wid = (blockIdx.x * blockDim.x + threadIdx.x) >> 6;
    if (wid >= N) return;
    int lane = threadIdx.x & 63;
    int grp = lane >> 4, sl = lane & 15;
    int s = rptr[wid];
    int n = rptr[wid + 1] - s;
    const uint4* hv = (const uint4*)Hs;   // 16B granules, 16 per row

    int cc = csr_col[s + lane];           // unconditional (csr_col padded +64)
    int ccreg = (lane < n) ? cc : N;      // pad lanes -> zero row
    uint4 vself = hv[(size_t)wid * 16 + sl];

    float a[8] = {0.f, 0.f, 0.f, 0.f, 0.f, 0.f, 0.f, 0.f};
    int nf = (n < 64) ? n : 64;
    for (int k0 = 0; k0 < nf; k0 += 16) {
        int i0 = k0 + grp;                // shuffle idx < 64 always
        int c0 = __shfl(ccreg, i0);
        int c1 = __shfl(ccreg, i0 + 4);
        int c2 = __shfl(ccreg, i0 + 8);
        int c3 = __shfl(ccreg, i0 + 12);
        uint4 v0 = hv[(size_t)c0 * 16 + sl];
        uint4 v1 = hv[(size_t)c1 * 16 + sl];
        uint4 v2 = hv[(size_t)c2 * 16 + sl];
        uint4 v3 = hv[(size_t)c3 * 16 + sl];
        ACC8(v0); ACC8(v1); ACC8(v2); ACC8(v3);
    }
    if (__builtin_expect(n > 64, 0)) {    // pathological high-degree fallback
        for (int idx = 64 + grp; idx < n; idx += 4) {
            int c = csr_col[s + idx];
            uint4 v = hv[(size_t)c * 16 + sl];
            ACC8(v);
        }
    }
    if (grp == 0) ACC8(vself);            // self-loop term

    #pragma unroll
    for (int j = 0; j < 8; ++j) {
        a[j] += __shfl_xor(a[j], 16);
        a[j] += __shfl_xor(a[j], 32);
    }
    float dr = dvals[wid];
    if (grp < 2) {
        float4 o = (grp == 0) ? make_float4(a[0], a[1], a[2], a[3])
                              : make_float4(a[4], a[5], a[6], a[7]);
        o.x *= dr; o.y *= dr; o.z *= dr; o.w *= dr;
        ((float4*)(out + (size_t)wid * D))[sl * 2 + grp] = o;
    }
}

extern "C" void kernel_launch(void* const* d_in, const int* in_sizes, int n_in,
                              void* d_out, int out_size, void* d_ws, size_t ws_size,
                              hipStream_t stream) {
    const float* x  = (const float*)d_in[0];
    const int*   ei = (const int*)d_in[1];
    const float* W  = (const float*)d_in[2];
    const float* b  = (const float*)d_in[3];
    float* out = (float*)d_out;
    int N = in_sizes[0] / D;
    int E = in_sizes[1] / 2;
    int NB = (N + BROWS - 1) / BROWS;        // 196
    int NCH = (E + CHUNK - 1) / CHUNK;       // 391

    int*            gcur    = (int*)d_ws;                // NBMAX
    int*            rptr    = gcur + NBMAX;              // N+1
    float*          dvals   = (float*)(rptr + N + 1);    // N+1 (dvals[N]=0 pad)
    int*            csr_col = (int*)(dvals + N + 1);     // E+64 (uncond read pad)
    unsigned*       ebuf    = (unsigned*)(csr_col + E + 64);  // NB*CAP
    unsigned short* Wbh     = (unsigned short*)(ebuf + (size_t)NB * CAP);  // 16384
    unsigned short* Wbl     = Wbh + D * D;                                  // 16384
    uintptr_t hs_addr = (uintptr_t)(Wbl + D * D);
    hs_addr = (hs_addr + 15) & ~(uintptr_t)15;
    unsigned short* Hs = (unsigned short*)hs_addr;  // (N+1)*D bf16; row N zeros

    hipMemsetAsync(gcur, 0, NBMAX * sizeof(int), stream);
    k_bin<<<NCH, 512, 0, stream>>>(ei, ei + E, E, gcur, ebuf, W, Wbh, Wbl);
    k_group<<<NB, 1024, 0, stream>>>(gcur, ebuf, N, NB, dvals, rptr, csr_col, Hs);
    k_gc<<<(N + 127) / 128, 256, 0, stream>>>(x, Wbh, Wbl, b, dvals, Hs, N);
    k_rows<<<(N + 3) / 4, 256, 0, stream>>>(Hs, rptr, csr_col, dvals, out, N);
}